// Round 1
// baseline (1589.374 us; speedup 1.0000x reference)
//
#include <hip/hip_runtime.h>

typedef unsigned short u16;
typedef unsigned int u32;
typedef __attribute__((ext_vector_type(8))) short short8;
typedef __attribute__((ext_vector_type(8))) u16 ushort8;
typedef __attribute__((ext_vector_type(4))) float f32x4;

#define T_TOK 2048
#define H_DIM 2048
#define NEXP 64
#define I_DIM 1408
#define SI_DIM 2816

__device__ __forceinline__ u16 f2bf(float f) {
    u32 u = __builtin_bit_cast(u32, f);
    u32 r = u + 0x7FFFu + ((u >> 16) & 1u);
    return (u16)(r >> 16);
}

__device__ __forceinline__ ushort8 cvt8(float4 a, float4 b) {
    ushort8 o;
    o[0] = f2bf(a.x); o[1] = f2bf(a.y); o[2] = f2bf(a.z); o[3] = f2bf(a.w);
    o[4] = f2bf(b.x); o[5] = f2bf(b.y); o[6] = f2bf(b.z); o[7] = f2bf(b.w);
    return o;
}

__device__ __forceinline__ f32x4 mfma16(short8 a, short8 b, f32x4 c) {
    return __builtin_amdgcn_mfma_f32_16x16x32_bf16(a, b, c, 0, 0, 0);
}

// ---------------- x -> bf16 ----------------
__global__ __launch_bounds__(256) void k_cvt(const float* __restrict__ x, u16* __restrict__ xb) {
    int i = (blockIdx.x * 256 + threadIdx.x) * 8;
    float4 v0 = *(const float4*)(x + i);
    float4 v1 = *(const float4*)(x + i + 4);
    *(ushort8*)(xb + i) = cvt8(v0, v1);
}

// ---------------- gating logits: f64 accumulation ----------------
__global__ __launch_bounds__(256) void k_gate_logits(const float* __restrict__ x,
        const float* __restrict__ gw, float* __restrict__ logits) {
    __shared__ float xs[8][65];
    __shared__ float wsh[64][65];
    int tid = threadIdx.x;
    int t0 = blockIdx.x * 8;
    double acc0 = 0.0, acc1 = 0.0;
    int e = tid & 63, tg = tid >> 6; // tg in [0,4)
    for (int k0 = 0; k0 < H_DIM; k0 += 64) {
        #pragma unroll
        for (int s = 0; s < 2; ++s) {
            int idx = s * 256 + tid;
            int r = idx >> 6, k = idx & 63;
            xs[r][k] = x[(size_t)(t0 + r) * H_DIM + k0 + k];
        }
        #pragma unroll
        for (int s = 0; s < 16; ++s) {
            int idx = s * 256 + tid;
            int r = idx >> 6, k = idx & 63;
            wsh[r][k] = gw[(size_t)r * H_DIM + k0 + k];
        }
        __syncthreads();
        #pragma unroll 8
        for (int k = 0; k < 64; ++k) {
            double wv = (double)wsh[e][k];
            acc0 += (double)xs[tg][k] * wv;
            acc1 += (double)xs[tg + 4][k] * wv;
        }
        __syncthreads();
    }
    logits[(size_t)(t0 + tg) * NEXP + e] = (float)acc0;
    logits[(size_t)(t0 + tg + 4) * NEXP + e] = (float)acc1;
}

// ---------------- per-token group-restricted top-k ----------------
__global__ __launch_bounds__(256) void k_topk(const float* __restrict__ logits,
        const float* __restrict__ ebias, int* __restrict__ topk_idx,
        float* __restrict__ topk_w, int* __restrict__ counts) {
    __shared__ float bsh[64];
    if (threadIdx.x < 64) bsh[threadIdx.x] = ebias[threadIdx.x];
    __syncthreads();
    int t = blockIdx.x * 256 + threadIdx.x;
    float sc[64];
    #pragma unroll
    for (int e2 = 0; e2 < 64; ++e2) {
        float lg = logits[(size_t)t * 64 + e2];
        sc[e2] = 1.0f / (1.0f + expf(-lg));
    }
    // group scores = sum of top-2 (scores + bias) per group of 8
    float gsc[8];
    #pragma unroll
    for (int g = 0; g < 8; ++g) {
        float m1 = -1e30f, m2 = -1e30f;
        #pragma unroll
        for (int j = 0; j < 8; ++j) {
            float v = sc[g * 8 + j] + bsh[g * 8 + j];
            if (v > m1) { m2 = m1; m1 = v; }
            else if (v > m2) { m2 = v; }
        }
        gsc[g] = m1 + m2;
    }
    // top-4 groups (ties -> lowest index, matches lax.top_k)
    u32 gmask = 0;
    #pragma unroll
    for (int it = 0; it < 4; ++it) {
        float best = -1e30f; int bi = 0;
        #pragma unroll
        for (int g = 0; g < 8; ++g) {
            bool ok = !((gmask >> g) & 1u);
            if (ok && gsc[g] > best) { best = gsc[g]; bi = g; }
        }
        gmask |= 1u << bi;
    }
    unsigned long long avail = 0ull;
    #pragma unroll
    for (int g = 0; g < 8; ++g)
        if ((gmask >> g) & 1u) avail |= (0xFFull << (g * 8));
    // top-8 experts among allowed groups
    float wsum = 0.f;
    int idx[8]; float wv[8];
    #pragma unroll
    for (int it = 0; it < 8; ++it) {
        float best = -1e30f, bw = 0.f; int bi = 0;
        #pragma unroll
        for (int e2 = 0; e2 < 64; ++e2) {
            bool ok = (avail >> e2) & 1ull;
            float v = sc[e2] + bsh[e2];
            if (ok && v > best) { best = v; bi = e2; bw = sc[e2]; }
        }
        avail &= ~(1ull << bi);
        idx[it] = bi; wv[it] = bw; wsum += bw;
    }
    float scale = 2.5f / (wsum + 1e-20f);
    #pragma unroll
    for (int it = 0; it < 8; ++it) {
        topk_idx[t * 8 + it] = idx[it];
        topk_w[t * 8 + it] = wv[it] * scale;
        atomicAdd(&counts[idx[it]], 1);
    }
}

// ---------------- prefix sum over 64 counts ----------------
__global__ void k_prefix(const int* __restrict__ counts, int* __restrict__ offsets) {
    if (threadIdx.x == 0) {
        int run = 0;
        for (int e = 0; e < 64; ++e) { offsets[e] = run; run += counts[e]; }
        offsets[64] = run;
    }
}

// ---------------- scatter (t,k) -> per-expert lists ----------------
__global__ __launch_bounds__(256) void k_scatter(const int* __restrict__ topk_idx,
        const float* __restrict__ topk_w, const int* __restrict__ offsets,
        int* __restrict__ fill, int* __restrict__ tok_list, float* __restrict__ w_list) {
    int gid = blockIdx.x * 256 + threadIdx.x; // [0, T*8)
    int t = gid >> 3;
    int e = topk_idx[gid];
    int pos = offsets[e] + atomicAdd(&fill[e], 1);
    tok_list[pos] = t;
    w_list[pos] = topk_w[gid];
}

// ---------------- fused gate+up+silu*mul grouped GEMM ----------------
// tile: 128 tokens x 64 I-rows, both gate and up; BK=64; 4 waves, each 32x64x{g,u}
__global__ __launch_bounds__(256) void k_gateup(
        const u16* __restrict__ xb,
        const float* __restrict__ gate_base, const float* __restrict__ up_base,
        const int* __restrict__ offsets, const int* __restrict__ tok_list,
        u16* __restrict__ inter, int Irows) {
    int i0 = blockIdx.x * 64;
    int m0 = blockIdx.y * 128;
    int e = blockIdx.z;
    int seg, n;
    if (offsets) { seg = offsets[e]; n = offsets[e + 1] - seg; }
    else { seg = 0; n = T_TOK; }
    if (m0 >= n) return;

    const float* Bg = gate_base + (size_t)e * Irows * H_DIM;
    const float* Bu = up_base + (size_t)e * Irows * H_DIM;

    __shared__ u16 Al[128 * 72];
    __shared__ u16 Bgl[64 * 72];
    __shared__ u16 Bul[64 * 72];

    int tid = threadIdx.x;
    int wv = tid >> 6, lane = tid & 63;

    f32x4 zero; zero[0] = 0.f; zero[1] = 0.f; zero[2] = 0.f; zero[3] = 0.f;
    f32x4 accg[2][4], accu[2][4];
    #pragma unroll
    for (int a = 0; a < 2; ++a)
        #pragma unroll
        for (int b = 0; b < 4; ++b) { accg[a][b] = zero; accu[a][b] = zero; }

    const u16* asrc[4]; int adst[4];
    #pragma unroll
    for (int s = 0; s < 4; ++s) {
        int idx = s * 256 + tid;
        int r = idx >> 3, ck = idx & 7;
        int p = m0 + r; if (p >= n) p = n - 1;
        int tok = tok_list ? tok_list[seg + p] : p;
        asrc[s] = xb + (size_t)tok * H_DIM + ck * 8;
        adst[s] = r * 72 + ck * 8;
    }
    const float* bgsrc[2]; const float* busrc[2]; int bdst[2];
    #pragma unroll
    for (int s = 0; s < 2; ++s) {
        int idx = s * 256 + tid;
        int r = idx >> 3, ck = idx & 7;
        bgsrc[s] = Bg + (size_t)(i0 + r) * H_DIM + ck * 8;
        busrc[s] = Bu + (size_t)(i0 + r) * H_DIM + ck * 8;
        bdst[s] = r * 72 + ck * 8;
    }

    int arow0 = (wv * 32 + (lane & 15)) * 72 + (lane >> 4) * 8;
    int arow1 = arow0 + 16 * 72;
    int brow = (lane & 15) * 72 + (lane >> 4) * 8;

    for (int k0 = 0; k0 < H_DIM; k0 += 64) {
        #pragma unroll
        for (int s = 0; s < 4; ++s)
            *(uint4*)(&Al[adst[s]]) = *(const uint4*)(asrc[s] + k0);
        #pragma unroll
        for (int s = 0; s < 2; ++s) {
            const float* pg = bgsrc[s] + k0;
            const float* pu = busrc[s] + k0;
            float4 g0 = *(const float4*)pg, g1 = *(const float4*)(pg + 4);
            float4 u0 = *(const float4*)pu, u1 = *(const float4*)(pu + 4);
            *(ushort8*)(&Bgl[bdst[s]]) = cvt8(g0, g1);
            *(ushort8*)(&Bul[bdst[s]]) = cvt8(u0, u1);
        }
        __syncthreads();
        #pragma unroll
        for (int ks = 0; ks < 2; ++ks) {
            short8 a0 = *(const short8*)(&Al[arow0 + ks * 32]);
            short8 a1 = *(const short8*)(&Al[arow1 + ks * 32]);
            #pragma unroll
            for (int fn = 0; fn < 4; ++fn) {
                short8 bg = *(const short8*)(&Bgl[brow + fn * 16 * 72 + ks * 32]);
                accg[0][fn] = mfma16(a0, bg, accg[0][fn]);
                accg[1][fn] = mfma16(a1, bg, accg[1][fn]);
                short8 bu = *(const short8*)(&Bul[brow + fn * 16 * 72 + ks * 32]);
                accu[0][fn] = mfma16(a0, bu, accu[0][fn]);
                accu[1][fn] = mfma16(a1, bu, accu[1][fn]);
            }
        }
        __syncthreads();
    }

    int r0 = (lane >> 4) * 4, cc = lane & 15;
    #pragma unroll
    for (int fm = 0; fm < 2; ++fm) {
        #pragma unroll
        for (int r = 0; r < 4; ++r) {
            int p = m0 + wv * 32 + fm * 16 + r0 + r;
            if (p < n) {
                size_t rowb = (size_t)(seg + p) * Irows + i0;
                #pragma unroll
                for (int fn = 0; fn < 4; ++fn) {
                    float g = accg[fm][fn][r], u = accu[fm][fn][r];
                    float val = g / (1.0f + expf(-g)) * u;
                    inter[rowb + fn * 16 + cc] = f2bf(val);
                }
            }
        }
    }
}

// ---------------- down-proj grouped GEMM, weighted atomic scatter ----------------
// tile: 128 rows x 128 H; BK=64
__global__ __launch_bounds__(256) void k_down(
        const u16* __restrict__ inter, int Kdim,
        const float* __restrict__ down_base,
        const int* __restrict__ offsets, const int* __restrict__ tok_list,
        const float* __restrict__ w_list,
        float* __restrict__ out) {
    int h0 = blockIdx.x * 128;
    int m0 = blockIdx.y * 128;
    int e = blockIdx.z;
    int seg, n;
    if (offsets) { seg = offsets[e]; n = offsets[e + 1] - seg; }
    else { seg = 0; n = T_TOK; }
    if (m0 >= n) return;

    const float* Bd = down_base + (size_t)e * H_DIM * Kdim;

    __shared__ u16 Al[128 * 72];
    __shared__ u16 Bl[128 * 72];

    int tid = threadIdx.x;
    int wv = tid >> 6, lane = tid & 63;

    f32x4 zero; zero[0] = 0.f; zero[1] = 0.f; zero[2] = 0.f; zero[3] = 0.f;
    f32x4 acc[2][8];
    #pragma unroll
    for (int a = 0; a < 2; ++a)
        #pragma unroll
        for (int b = 0; b < 8; ++b) acc[a][b] = zero;

    const u16* asrc[4]; const float* bsrc[4]; int sdst[4];
    #pragma unroll
    for (int s = 0; s < 4; ++s) {
        int idx = s * 256 + tid;
        int r = idx >> 3, ck = idx & 7;
        int p = m0 + r; if (p >= n) p = n - 1;
        asrc[s] = inter + (size_t)(seg + p) * Kdim + ck * 8;
        bsrc[s] = Bd + (size_t)(h0 + r) * Kdim + ck * 8;
        sdst[s] = r * 72 + ck * 8;
    }

    int arow0 = (wv * 32 + (lane & 15)) * 72 + (lane >> 4) * 8;
    int arow1 = arow0 + 16 * 72;
    int brow = (lane & 15) * 72 + (lane >> 4) * 8;

    for (int k0 = 0; k0 < Kdim; k0 += 64) {
        #pragma unroll
        for (int s = 0; s < 4; ++s) {
            *(uint4*)(&Al[sdst[s]]) = *(const uint4*)(asrc[s] + k0);
            const float* pb = bsrc[s] + k0;
            float4 b0 = *(const float4*)pb, b1 = *(const float4*)(pb + 4);
            *(ushort8*)(&Bl[sdst[s]]) = cvt8(b0, b1);
        }
        __syncthreads();
        #pragma unroll
        for (int ks = 0; ks < 2; ++ks) {
            short8 a0 = *(const short8*)(&Al[arow0 + ks * 32]);
            short8 a1 = *(const short8*)(&Al[arow1 + ks * 32]);
            #pragma unroll
            for (int fn = 0; fn < 8; ++fn) {
                short8 b = *(const short8*)(&Bl[brow + fn * 16 * 72 + ks * 32]);
                acc[0][fn] = mfma16(a0, b, acc[0][fn]);
                acc[1][fn] = mfma16(a1, b, acc[1][fn]);
            }
        }
        __syncthreads();
    }

    int r0 = (lane >> 4) * 4, cc = lane & 15;
    #pragma unroll
    for (int fm = 0; fm < 2; ++fm) {
        #pragma unroll
        for (int r = 0; r < 4; ++r) {
            int p = m0 + wv * 32 + fm * 16 + r0 + r;
            if (p < n) {
                int tok = tok_list ? tok_list[seg + p] : p;
                float wt = w_list ? w_list[seg + p] : 1.0f;
                size_t ob = (size_t)tok * H_DIM + h0 + cc;
                #pragma unroll
                for (int fn = 0; fn < 8; ++fn)
                    atomicAdd(&out[ob + fn * 16], acc[fm][fn][r] * wt);
            }
        }
    }
}

extern "C" void kernel_launch(void* const* d_in, const int* in_sizes, int n_in,
                              void* d_out, int out_size, void* d_ws, size_t ws_size,
                              hipStream_t stream) {
    const float* x         = (const float*)d_in[0];
    const float* gate_w    = (const float*)d_in[1];
    const float* e_bias    = (const float*)d_in[2];
    const float* gate_proj = (const float*)d_in[3];
    const float* up_proj   = (const float*)d_in[4];
    const float* down_proj = (const float*)d_in[5];
    const float* sgw       = (const float*)d_in[6];
    const float* suw       = (const float*)d_in[7];
    const float* sdw       = (const float*)d_in[8];
    float* out = (float*)d_out;

    char* ws = (char*)d_ws;
    size_t off = 0;
    auto alloc = [&](size_t bytes) -> char* {
        char* p = ws + off;
        off += (bytes + 255) & ~(size_t)255;
        return p;
    };
    float* logits   = (float*)alloc((size_t)T_TOK * 64 * 4);
    int*   topk_idx = (int*)  alloc((size_t)T_TOK * 8 * 4);
    float* topk_w   = (float*)alloc((size_t)T_TOK * 8 * 4);
    int*   counts   = (int*)  alloc(256);   // [64]
    int*   offsets  = (int*)  alloc(512);   // [65]
    int*   fill     = (int*)  alloc(256);   // [64]
    int*   tok_list = (int*)  alloc((size_t)T_TOK * 8 * 4);
    float* w_list   = (float*)alloc((size_t)T_TOK * 8 * 4);
    u16*   xb       = (u16*)  alloc((size_t)T_TOK * H_DIM * 2);
    u16*   inter    = (u16*)  alloc((size_t)T_TOK * 8 * I_DIM * 2); // reused for shared (T*SI*2 < this)

    hipMemsetAsync(d_out, 0, (size_t)out_size * 4, stream);
    hipMemsetAsync(counts, 0, 1024, stream); // counts + offsets + fill (contiguous)

    k_cvt<<<(T_TOK * H_DIM) / 2048, 256, 0, stream>>>(x, xb);
    k_gate_logits<<<T_TOK / 8, 256, 0, stream>>>(x, gate_w, logits);
    k_topk<<<T_TOK / 256, 256, 0, stream>>>(logits, e_bias, topk_idx, topk_w, counts);
    k_prefix<<<1, 64, 0, stream>>>(counts, offsets);
    k_scatter<<<(T_TOK * 8) / 256, 256, 0, stream>>>(topk_idx, topk_w, offsets, fill, tok_list, w_list);

    // routed experts
    k_gateup<<<dim3(I_DIM / 64, 16, 64), 256, 0, stream>>>(
        xb, gate_proj, up_proj, offsets, tok_list, inter, I_DIM);
    k_down<<<dim3(H_DIM / 128, 16, 64), 256, 0, stream>>>(
        inter, I_DIM, down_proj, offsets, tok_list, w_list, out);

    // shared experts (identity token list, unit weight)
    k_gateup<<<dim3(SI_DIM / 64, 16, 1), 256, 0, stream>>>(
        xb, sgw, suw, nullptr, nullptr, inter, SI_DIM);
    k_down<<<dim3(H_DIM / 128, 16, 1), 256, 0, stream>>>(
        inter, SI_DIM, sdw, nullptr, nullptr, nullptr, out);
}